// Round 6
// baseline (495.733 us; speedup 1.0000x reference)
//
#include <hip/hip_runtime.h>

#define NEG_SLOPE 0.01f

constexpr int N_NODES_C = 50000;
constexpr int N_EDGES_C = 800000;
constexpr int M_PAD = 50048;  // 391 * 128

typedef short bf16x8 __attribute__((ext_vector_type(8)));
typedef float f32x4 __attribute__((ext_vector_type(4)));

__device__ inline unsigned short f2bf(float f) {
  unsigned int u = __float_as_uint(f);
  u += 0x7FFF + ((u >> 16) & 1);  // round-to-nearest-even
  return (unsigned short)(u >> 16);
}
__device__ inline float bf2f(unsigned int h16) {
  return __uint_as_float(h16 << 16);
}

// ---------------- fused preprocessing ----------------
// blocks [0,6256): conv_x   [6256,6512): w1T   [6512,6640): w2T   [6640,9765): histogram
constexpr int NB_CONVX = (M_PAD * 32) / 256;          // 6256
constexpr int NB_W1 = (256 * 256) / 256;              // 256
constexpr int NB_W2 = (256 * 128) / 256;              // 128
constexpr int NB_HIST = N_EDGES_C / 256;              // 3125
constexpr int NB_PRE = NB_CONVX + NB_W1 + NB_W2 + NB_HIST;

__global__ __launch_bounds__(256) void pre_kernel(
    const float* __restrict__ x, const float* __restrict__ w1,
    const float* __restrict__ w2, const int* __restrict__ dst,
    unsigned short* __restrict__ xb, unsigned short* __restrict__ w1T,
    unsigned short* __restrict__ w2T, int* __restrict__ counts) {
  const int bx = blockIdx.x;
  const int tid = threadIdx.x;
  if (bx < NB_CONVX) {
    int idx = bx * 256 + tid;
    int row = idx >> 5;
    int c8 = (idx & 31) << 3;
    uint4 v;
    if (row < N_NODES_C) {
      const float4* p = (const float4*)(x + (size_t)row * 256 + c8);
      float4 a = p[0], b = p[1];
      v.x = f2bf(a.x) | ((unsigned)f2bf(a.y) << 16);
      v.y = f2bf(a.z) | ((unsigned)f2bf(a.w) << 16);
      v.z = f2bf(b.x) | ((unsigned)f2bf(b.y) << 16);
      v.w = f2bf(b.z) | ((unsigned)f2bf(b.w) << 16);
    } else {
      v = make_uint4(0, 0, 0, 0);
    }
    *(uint4*)(xb + (size_t)row * 256 + c8) = v;
  } else if (bx < NB_CONVX + NB_W1) {
    int idx = (bx - NB_CONVX) * 256 + tid;  // over [N=256][K=256]
    int n = idx >> 8, k = idx & 255;
    w1T[idx] = f2bf(w1[(size_t)k * 256 + n]);
  } else if (bx < NB_CONVX + NB_W1 + NB_W2) {
    int idx = (bx - NB_CONVX - NB_W1) * 256 + tid;  // over [N=128][K=256]
    int n = idx >> 8, k = idx & 255;
    w2T[idx] = f2bf(w2[(size_t)k * 128 + n]);
  } else {
    int e = (bx - NB_CONVX - NB_W1 - NB_W2) * 256 + tid;
    atomicAdd(&counts[dst[e]], 1);
  }
}

// ---------------- hierarchical scan ----------------
constexpr int N_SCAN_BLKS = (N_NODES_C + 255) / 256;  // 196

__global__ __launch_bounds__(256) void scan_phase_a(const int* __restrict__ counts,
                                                    int* __restrict__ partial,
                                                    int* __restrict__ blk_sums) {
  __shared__ int s[256];
  const int t = threadIdx.x;
  const int i = blockIdx.x * 256 + t;
  const int v = (i < N_NODES_C) ? counts[i] : 0;
  s[t] = v;
  __syncthreads();
  for (int off = 1; off < 256; off <<= 1) {
    int u = (t >= off) ? s[t - off] : 0;
    __syncthreads();
    s[t] += u;
    __syncthreads();
  }
  if (i < N_NODES_C) partial[i] = s[t] - v;
  if (t == 255) blk_sums[blockIdx.x] = s[255];
}

__global__ __launch_bounds__(256) void scan_phase_b(const int* __restrict__ blk_sums,
                                                    int* __restrict__ blk_off) {
  __shared__ int s[256];
  const int t = threadIdx.x;
  const int v = (t < N_SCAN_BLKS) ? blk_sums[t] : 0;
  s[t] = v;
  __syncthreads();
  for (int off = 1; off < 256; off <<= 1) {
    int u = (t >= off) ? s[t - off] : 0;
    __syncthreads();
    s[t] += u;
    __syncthreads();
  }
  if (t < N_SCAN_BLKS) blk_off[t] = s[t] - v;
}

__global__ __launch_bounds__(256) void scan_phase_c(const int* __restrict__ partial,
                                                    const int* __restrict__ blk_off,
                                                    int* __restrict__ row_ptr,
                                                    int* __restrict__ cursor) {
  const int i = blockIdx.x * 256 + threadIdx.x;
  if (i < N_NODES_C) {
    const int r = partial[i] + blk_off[blockIdx.x];
    row_ptr[i] = r;
    cursor[i] = r;
  }
  if (i == 0) row_ptr[N_NODES_C] = N_EDGES_C;
}

__global__ __launch_bounds__(256) void fill_kernel(const int* __restrict__ src,
                                                   const int* __restrict__ dst,
                                                   const float* __restrict__ ew,
                                                   int* __restrict__ cursor,
                                                   uint2* __restrict__ s_meta) {
  int e = blockIdx.x * 256 + threadIdx.x;
  if (e < N_EDGES_C) {
    int p = atomicAdd(&cursor[dst[e]], 1);
    uint2 m;
    m.x = (unsigned)src[e];
    m.y = __float_as_uint(ew[e]);
    s_meta[p] = m;
  }
}

// ---------------- bf16 MFMA GEMM with SLICED output ----------------
// C_sliced[slice][M_PAD][32] where slice = col/32

#define GLOAD_LDS16(g, l)                                              \
  __builtin_amdgcn_global_load_lds(                                    \
      (__attribute__((address_space(1))) void*)(g),                    \
      (__attribute__((address_space(3))) void*)(l), 16, 0, 0)

__global__ __launch_bounds__(256) void gemm_bf16_kernel(
    const unsigned short* __restrict__ A,   // [M_PAD][256] bf16
    const unsigned short* __restrict__ BT,  // [N][256] bf16
    unsigned short* __restrict__ C,         // [N/32][M_PAD][32] bf16 sliced
    int N) {
  constexpr int K = 256;
  __shared__ short Asm[128 * 32];
  __shared__ short Bsm[128 * 32];
  const int tid = threadIdx.x;
  const int lane = tid & 63, wave = tid >> 6;
  const int wm = wave & 1, wn = wave >> 1;
  const int row0 = blockIdx.y * 128, col0 = blockIdx.x * 128;

  const int ch0 = wave * 2, ch1 = wave * 2 + 1;
  const int o0 = ch0 * 512 + lane * 8;
  const int o1 = ch1 * 512 + lane * 8;
  const int r0 = o0 >> 5, c0 = o0 & 31;
  const int r1 = o1 >> 5, c1 = o1 & 31;

  f32x4 acc[4][4] = {};

  for (int k0 = 0; k0 < K; k0 += 32) {
    GLOAD_LDS16(A + (size_t)(row0 + r0) * K + k0 + c0, &Asm[ch0 * 512]);
    GLOAD_LDS16(A + (size_t)(row0 + r1) * K + k0 + c1, &Asm[ch1 * 512]);
    GLOAD_LDS16(BT + (size_t)(col0 + r0) * K + k0 + c0, &Bsm[ch0 * 512]);
    GLOAD_LDS16(BT + (size_t)(col0 + r1) * K + k0 + c1, &Bsm[ch1 * 512]);
    __builtin_amdgcn_s_waitcnt(0);
    __syncthreads();

    bf16x8 af[4], bf[4];
#pragma unroll
    for (int mt = 0; mt < 4; ++mt)
      af[mt] = *(const bf16x8*)&Asm[(wm * 64 + mt * 16 + (lane & 15)) * 32 + (lane >> 4) * 8];
#pragma unroll
    for (int nt = 0; nt < 4; ++nt)
      bf[nt] = *(const bf16x8*)&Bsm[(wn * 64 + nt * 16 + (lane & 15)) * 32 + (lane >> 4) * 8];
#pragma unroll
    for (int mt = 0; mt < 4; ++mt)
#pragma unroll
      for (int nt = 0; nt < 4; ++nt)
        acc[mt][nt] = __builtin_amdgcn_mfma_f32_16x16x32_bf16(af[mt], bf[nt], acc[mt][nt], 0, 0, 0);
    __syncthreads();
  }

  const int cl = lane & 15, rq = (lane >> 4) * 4;
#pragma unroll
  for (int mt = 0; mt < 4; ++mt) {
    const int rbase = row0 + wm * 64 + mt * 16 + rq;
#pragma unroll
    for (int nt = 0; nt < 4; ++nt) {
      const int col = col0 + wn * 64 + nt * 16 + cl;
      const size_t sbase = ((size_t)(col >> 5) * M_PAD) * 32 + (col & 31);
#pragma unroll
      for (int i = 0; i < 4; ++i)
        C[sbase + (size_t)(rbase + i) * 32] = f2bf(acc[mt][nt][i]);
    }
  }
}

// ---------------- sliced gather aggregation ----------------
// One wave = one (node, slice-of-32-dims). Lane l: edge slot l>>2, dim group (l&3)*8.
// blockIdx & (NSLICE-1) = slice  -> XCD-striped so each XCD's L2 caches one 3.2MB slice.

template <int NSLICE, int OUT_D, bool OUT_BF16>
__global__ __launch_bounds__(256) void agg_sliced_kernel(
    const unsigned short* __restrict__ supS,  // [NSLICE][M_PAD][32]
    const uint2* __restrict__ s_meta, const int* __restrict__ row_ptr,
    const float* __restrict__ bias, unsigned short* __restrict__ out_bf,
    float* __restrict__ out_f, int n_total) {
  const int bx = blockIdx.x;
  const int slice = bx & (NSLICE - 1);
  const int group = bx / NSLICE;
  const int lane = threadIdx.x & 63;
  const int n = group * 4 + (threadIdx.x >> 6);
  if (n >= n_total) return;
  const bool valid = n < N_NODES_C;

  const int dimg = lane & 3;   // 8-dim group within the 32-dim slice
  const int slot = lane >> 2;  // edge slot 0..15
  const unsigned short* tab = supS + (size_t)slice * M_PAD * 32;

  float acc[8] = {};

  if (valid) {
    const int start = row_ptr[n];
    const int end = row_ptr[n + 1];
    for (int j = start; j < end; j += 16) {
      const int idx = j + slot;
      if (idx < end) {
        uint2 m = s_meta[idx];
        const int s = (int)m.x;
        const float wt = __uint_as_float(m.y);
        uint4 v = *(const uint4*)(tab + (size_t)s * 32 + dimg * 8);
        acc[0] += bf2f(v.x & 0xffffu) * wt;
        acc[1] += bf2f(v.x >> 16) * wt;
        acc[2] += bf2f(v.y & 0xffffu) * wt;
        acc[3] += bf2f(v.y >> 16) * wt;
        acc[4] += bf2f(v.z & 0xffffu) * wt;
        acc[5] += bf2f(v.z >> 16) * wt;
        acc[6] += bf2f(v.w & 0xffffu) * wt;
        acc[7] += bf2f(v.w >> 16) * wt;
      }
    }
  }

  // reduce over the 16 edge slots (lanes with equal lane&3)
#pragma unroll
  for (int j = 0; j < 8; ++j) {
    acc[j] += __shfl_xor(acc[j], 4);
    acc[j] += __shfl_xor(acc[j], 8);
    acc[j] += __shfl_xor(acc[j], 16);
    acc[j] += __shfl_xor(acc[j], 32);
  }

  if (lane < 4) {
    const int dbase = slice * 32 + lane * 8;
    if (OUT_BF16) {
      unsigned short o[8];
#pragma unroll
      for (int j = 0; j < 8; ++j) {
        if (valid) {
          float v = acc[j] + bias[dbase + j];
          v = v >= 0.f ? v : NEG_SLOPE * v;
          o[j] = f2bf(v);
        } else {
          o[j] = 0;
        }
      }
      uint4 pk;
      pk.x = o[0] | ((unsigned)o[1] << 16);
      pk.y = o[2] | ((unsigned)o[3] << 16);
      pk.z = o[4] | ((unsigned)o[5] << 16);
      pk.w = o[6] | ((unsigned)o[7] << 16);
      *(uint4*)(out_bf + (size_t)n * OUT_D + dbase) = pk;
    } else if (valid) {
      float r[8];
#pragma unroll
      for (int j = 0; j < 8; ++j) {
        float v = acc[j] + bias[dbase + j];
        r[j] = v >= 0.f ? v : NEG_SLOPE * v;
      }
      *(float4*)(out_f + (size_t)n * OUT_D + dbase) = make_float4(r[0], r[1], r[2], r[3]);
      *(float4*)(out_f + (size_t)n * OUT_D + dbase + 4) = make_float4(r[4], r[5], r[6], r[7]);
    }
  }
}

// ---------------- launch ----------------

extern "C" void kernel_launch(void* const* d_in, const int* in_sizes, int n_in,
                              void* d_out, int out_size, void* d_ws, size_t ws_size,
                              hipStream_t stream) {
  const float* x  = (const float*)d_in[0];   // [50000,256]
  const float* w1 = (const float*)d_in[1];   // [256,256]
  const float* b1 = (const float*)d_in[2];   // [256]
  const float* w2 = (const float*)d_in[3];   // [256,128]
  const float* b2 = (const float*)d_in[4];   // [128]
  const int*   src = (const int*)d_in[5];    // [800000]
  const int*   dst = (const int*)d_in[6];    // [800000]
  const float* ew  = (const float*)d_in[7];  // [800000]
  float* out = (float*)d_out;                // [50000,128]

  unsigned short* xb   = (unsigned short*)d_ws;              // M_PAD*256
  unsigned short* a2b  = xb + (size_t)M_PAD * 256;           // M_PAD*256
  unsigned short* sup1 = a2b + (size_t)M_PAD * 256;          // M_PAD*256 (sliced 8x[M_PAD][32])
  unsigned short* sup2 = sup1 + (size_t)M_PAD * 256;         // M_PAD*128 (sliced 4x[M_PAD][32])
  unsigned short* w1T  = sup2 + (size_t)M_PAD * 128;         // 256*256
  unsigned short* w2T  = w1T + 256 * 256;                    // 128*256
  int* counts  = (int*)(w2T + 128 * 256);                    // 50000
  int* cursor  = counts + N_NODES_C;                         // 50000
  int* row_ptr = cursor + N_NODES_C;                         // 50001
  int* partial = row_ptr + (N_NODES_C + 1);                  // 50000
  int* blk_sums= partial + N_NODES_C;                        // 256
  int* blk_off = blk_sums + 256;                             // 256
  uint2* s_meta = (uint2*)(blk_off + 256 + 2);               // 800000 * 8B

  const int EB = (N_EDGES_C + 255) / 256;

  // preprocessing: memset counts, then fused {conv_x, w1T, w2T, histogram}
  hipMemsetAsync(counts, 0, N_NODES_C * sizeof(int), stream);
  pre_kernel<<<NB_PRE, 256, 0, stream>>>(x, w1, w2, dst, xb, w1T, w2T, counts);

  // CSR scan + fill
  scan_phase_a<<<N_SCAN_BLKS, 256, 0, stream>>>(counts, partial, blk_sums);
  scan_phase_b<<<1, 256, 0, stream>>>(blk_sums, blk_off);
  scan_phase_c<<<N_SCAN_BLKS, 256, 0, stream>>>(partial, blk_off, row_ptr, cursor);
  fill_kernel<<<EB, 256, 0, stream>>>(src, dst, ew, cursor, s_meta);

  // layer 1: sup1(sliced) = xb @ w1 ; a2b = bf16(lrelu(agg(sup1) + b1))
  gemm_bf16_kernel<<<dim3(2, M_PAD / 128), 256, 0, stream>>>(xb, w1T, sup1, 256);
  agg_sliced_kernel<8, 256, true><<<(M_PAD / 4) * 8, 256, 0, stream>>>(
      sup1, s_meta, row_ptr, b1, a2b, nullptr, M_PAD);

  // layer 2: sup2(sliced) = a2b @ w2 ; out = lrelu(agg(sup2) + b2) fp32
  gemm_bf16_kernel<<<dim3(1, M_PAD / 128), 256, 0, stream>>>(a2b, w2T, sup2, 128);
  agg_sliced_kernel<4, 128, false><<<((N_NODES_C + 3) / 4) * 4, 256, 0, stream>>>(
      sup2, s_meta, row_ptr, b2, nullptr, out, N_NODES_C);
}

// Round 7
// 332.141 us; speedup vs baseline: 1.4925x; 1.4925x over previous
//
#include <hip/hip_runtime.h>

#define NEG_SLOPE 0.01f

constexpr int N_NODES_C = 50000;
constexpr int N_EDGES_C = 800000;
constexpr int M_PAD = 50048;  // 391 * 128

typedef short bf16x8 __attribute__((ext_vector_type(8)));
typedef float f32x4 __attribute__((ext_vector_type(4)));

__device__ inline unsigned short f2bf(float f) {
  unsigned int u = __float_as_uint(f);
  u += 0x7FFF + ((u >> 16) & 1);  // round-to-nearest-even
  return (unsigned short)(u >> 16);
}
__device__ inline float bf2f(unsigned int h16) {
  return __uint_as_float(h16 << 16);
}

// ---------------- fused preprocessing ----------------
constexpr int NB_CONVX = (M_PAD * 32) / 256;          // 6256
constexpr int NB_W1 = (256 * 256) / 256;              // 256
constexpr int NB_W2 = (256 * 128) / 256;              // 128
constexpr int NB_HIST = N_EDGES_C / 256;              // 3125
constexpr int NB_PRE = NB_CONVX + NB_W1 + NB_W2 + NB_HIST;

__global__ __launch_bounds__(256) void pre_kernel(
    const float* __restrict__ x, const float* __restrict__ w1,
    const float* __restrict__ w2, const int* __restrict__ dst,
    unsigned short* __restrict__ xb, unsigned short* __restrict__ w1T,
    unsigned short* __restrict__ w2T, int* __restrict__ counts) {
  const int bx = blockIdx.x;
  const int tid = threadIdx.x;
  if (bx < NB_CONVX) {
    int idx = bx * 256 + tid;
    int row = idx >> 5;
    int c8 = (idx & 31) << 3;
    uint4 v;
    if (row < N_NODES_C) {
      const float4* p = (const float4*)(x + (size_t)row * 256 + c8);
      float4 a = p[0], b = p[1];
      v.x = f2bf(a.x) | ((unsigned)f2bf(a.y) << 16);
      v.y = f2bf(a.z) | ((unsigned)f2bf(a.w) << 16);
      v.z = f2bf(b.x) | ((unsigned)f2bf(b.y) << 16);
      v.w = f2bf(b.z) | ((unsigned)f2bf(b.w) << 16);
    } else {
      v = make_uint4(0, 0, 0, 0);
    }
    *(uint4*)(xb + (size_t)row * 256 + c8) = v;
  } else if (bx < NB_CONVX + NB_W1) {
    int idx = (bx - NB_CONVX) * 256 + tid;  // over [N=256][K=256]
    int n = idx >> 8, k = idx & 255;
    w1T[idx] = f2bf(w1[(size_t)k * 256 + n]);
  } else if (bx < NB_CONVX + NB_W1 + NB_W2) {
    int idx = (bx - NB_CONVX - NB_W1) * 256 + tid;  // over [N=128][K=256]
    int n = idx >> 8, k = idx & 255;
    w2T[idx] = f2bf(w2[(size_t)k * 128 + n]);
  } else {
    int e = (bx - NB_CONVX - NB_W1 - NB_W2) * 256 + tid;
    atomicAdd(&counts[dst[e]], 1);
  }
}

// ---------------- hierarchical scan ----------------
constexpr int N_SCAN_BLKS = (N_NODES_C + 255) / 256;  // 196

__global__ __launch_bounds__(256) void scan_phase_a(const int* __restrict__ counts,
                                                    int* __restrict__ partial,
                                                    int* __restrict__ blk_sums) {
  __shared__ int s[256];
  const int t = threadIdx.x;
  const int i = blockIdx.x * 256 + t;
  const int v = (i < N_NODES_C) ? counts[i] : 0;
  s[t] = v;
  __syncthreads();
  for (int off = 1; off < 256; off <<= 1) {
    int u = (t >= off) ? s[t - off] : 0;
    __syncthreads();
    s[t] += u;
    __syncthreads();
  }
  if (i < N_NODES_C) partial[i] = s[t] - v;
  if (t == 255) blk_sums[blockIdx.x] = s[255];
}

__global__ __launch_bounds__(256) void scan_phase_b(const int* __restrict__ blk_sums,
                                                    int* __restrict__ blk_off) {
  __shared__ int s[256];
  const int t = threadIdx.x;
  const int v = (t < N_SCAN_BLKS) ? blk_sums[t] : 0;
  s[t] = v;
  __syncthreads();
  for (int off = 1; off < 256; off <<= 1) {
    int u = (t >= off) ? s[t - off] : 0;
    __syncthreads();
    s[t] += u;
    __syncthreads();
  }
  if (t < N_SCAN_BLKS) blk_off[t] = s[t] - v;
}

__global__ __launch_bounds__(256) void scan_phase_c(const int* __restrict__ partial,
                                                    const int* __restrict__ blk_off,
                                                    int* __restrict__ row_ptr,
                                                    int* __restrict__ cursor) {
  const int i = blockIdx.x * 256 + threadIdx.x;
  if (i < N_NODES_C) {
    const int r = partial[i] + blk_off[blockIdx.x];
    row_ptr[i] = r;
    cursor[i] = r;
  }
  if (i == 0) row_ptr[N_NODES_C] = N_EDGES_C;
}

__global__ __launch_bounds__(256) void fill_kernel(const int* __restrict__ src,
                                                   const int* __restrict__ dst,
                                                   const float* __restrict__ ew,
                                                   int* __restrict__ cursor,
                                                   uint2* __restrict__ s_meta) {
  int e = blockIdx.x * 256 + threadIdx.x;
  if (e < N_EDGES_C) {
    int p = atomicAdd(&cursor[dst[e]], 1);
    uint2 m;
    m.x = (unsigned)src[e];
    m.y = __float_as_uint(ew[e]);
    s_meta[p] = m;
  }
}

// ---------------- bf16 MFMA GEMM with SLICED output ----------------
// C_sliced[slice][M_PAD][32] where slice = col/32

#define GLOAD_LDS16(g, l)                                              \
  __builtin_amdgcn_global_load_lds(                                    \
      (__attribute__((address_space(1))) void*)(g),                    \
      (__attribute__((address_space(3))) void*)(l), 16, 0, 0)

__global__ __launch_bounds__(256) void gemm_bf16_kernel(
    const unsigned short* __restrict__ A,   // [M_PAD][256] bf16
    const unsigned short* __restrict__ BT,  // [N][256] bf16
    unsigned short* __restrict__ C,         // [N/32][M_PAD][32] bf16 sliced
    int N) {
  constexpr int K = 256;
  __shared__ short Asm[128 * 32];
  __shared__ short Bsm[128 * 32];
  const int tid = threadIdx.x;
  const int lane = tid & 63, wave = tid >> 6;
  const int wm = wave & 1, wn = wave >> 1;
  const int row0 = blockIdx.y * 128, col0 = blockIdx.x * 128;

  const int ch0 = wave * 2, ch1 = wave * 2 + 1;
  const int o0 = ch0 * 512 + lane * 8;
  const int o1 = ch1 * 512 + lane * 8;
  const int r0 = o0 >> 5, c0 = o0 & 31;
  const int r1 = o1 >> 5, c1 = o1 & 31;

  f32x4 acc[4][4] = {};

  for (int k0 = 0; k0 < K; k0 += 32) {
    GLOAD_LDS16(A + (size_t)(row0 + r0) * K + k0 + c0, &Asm[ch0 * 512]);
    GLOAD_LDS16(A + (size_t)(row0 + r1) * K + k0 + c1, &Asm[ch1 * 512]);
    GLOAD_LDS16(BT + (size_t)(col0 + r0) * K + k0 + c0, &Bsm[ch0 * 512]);
    GLOAD_LDS16(BT + (size_t)(col0 + r1) * K + k0 + c1, &Bsm[ch1 * 512]);
    __builtin_amdgcn_s_waitcnt(0);
    __syncthreads();

    bf16x8 af[4], bf[4];
#pragma unroll
    for (int mt = 0; mt < 4; ++mt)
      af[mt] = *(const bf16x8*)&Asm[(wm * 64 + mt * 16 + (lane & 15)) * 32 + (lane >> 4) * 8];
#pragma unroll
    for (int nt = 0; nt < 4; ++nt)
      bf[nt] = *(const bf16x8*)&Bsm[(wn * 64 + nt * 16 + (lane & 15)) * 32 + (lane >> 4) * 8];
#pragma unroll
    for (int mt = 0; mt < 4; ++mt)
#pragma unroll
      for (int nt = 0; nt < 4; ++nt)
        acc[mt][nt] = __builtin_amdgcn_mfma_f32_16x16x32_bf16(af[mt], bf[nt], acc[mt][nt], 0, 0, 0);
    __syncthreads();
  }

  const int cl = lane & 15, rq = (lane >> 4) * 4;
#pragma unroll
  for (int mt = 0; mt < 4; ++mt) {
    const int rbase = row0 + wm * 64 + mt * 16 + rq;
#pragma unroll
    for (int nt = 0; nt < 4; ++nt) {
      const int col = col0 + wn * 64 + nt * 16 + cl;
      const size_t sbase = ((size_t)(col >> 5) * M_PAD) * 32 + (col & 31);
#pragma unroll
      for (int i = 0; i < 4; ++i)
        C[sbase + (size_t)(rbase + i) * 32] = f2bf(acc[mt][nt][i]);
    }
  }
}

// ---------------- quad-per-node sliced aggregation ----------------
// 4 lanes per node ("quad"); lane owns 8 dims (uint4) of the 32-dim slice and
// accumulates over the node's edges SEQUENTIALLY -> no cross-lane reduction.
// Wave = 16 nodes; block = 64 nodes; blockIdx & (NSLICE-1) = slice (XCD stripe).

__device__ inline void fma8(float* acc, uint4 v, float wt) {
  acc[0] += bf2f(v.x & 0xffffu) * wt;
  acc[1] += bf2f(v.x >> 16) * wt;
  acc[2] += bf2f(v.y & 0xffffu) * wt;
  acc[3] += bf2f(v.y >> 16) * wt;
  acc[4] += bf2f(v.z & 0xffffu) * wt;
  acc[5] += bf2f(v.z >> 16) * wt;
  acc[6] += bf2f(v.w & 0xffffu) * wt;
  acc[7] += bf2f(v.w >> 16) * wt;
}

template <int NSLICE, int OUT_D, bool OUT_BF16>
__global__ __launch_bounds__(256) void agg_quad_kernel(
    const unsigned short* __restrict__ supS,  // [NSLICE][M_PAD][32]
    const uint2* __restrict__ s_meta, const int* __restrict__ row_ptr,
    const float* __restrict__ bias, unsigned short* __restrict__ out_bf,
    float* __restrict__ out_f, int n_total) {
  const int bx = blockIdx.x;
  const int slice = bx & (NSLICE - 1);
  const int group = bx / NSLICE;
  const int tid = threadIdx.x;
  const int quad = tid >> 2;   // 0..63: node within group
  const int dimg = tid & 3;    // 8-dim octet within the 32-dim slice
  const int n = group * 64 + quad;
  if (n >= n_total) return;
  const bool valid = n < N_NODES_C;
  const unsigned short* tab = supS + (size_t)slice * M_PAD * 32;

  float acc[8] = {};
  if (valid) {
    int j = row_ptr[n];
    const int end = row_ptr[n + 1];
    for (; j + 2 <= end; j += 2) {
      uint2 m0 = s_meta[j];
      uint2 m1 = s_meta[j + 1];
      uint4 v0 = *(const uint4*)(tab + m0.x * 32 + dimg * 8);
      uint4 v1 = *(const uint4*)(tab + m1.x * 32 + dimg * 8);
      fma8(acc, v0, __uint_as_float(m0.y));
      fma8(acc, v1, __uint_as_float(m1.y));
    }
    if (j < end) {
      uint2 m0 = s_meta[j];
      uint4 v0 = *(const uint4*)(tab + m0.x * 32 + dimg * 8);
      fma8(acc, v0, __uint_as_float(m0.y));
    }
  }

  const int dbase = slice * 32 + dimg * 8;
  if (OUT_BF16) {
    unsigned short o[8];
#pragma unroll
    for (int j = 0; j < 8; ++j) {
      float v = acc[j] + bias[dbase + j];
      v = v >= 0.f ? v : NEG_SLOPE * v;
      o[j] = f2bf(v);
    }
    uint4 pk;
    pk.x = o[0] | ((unsigned)o[1] << 16);
    pk.y = o[2] | ((unsigned)o[3] << 16);
    pk.z = o[4] | ((unsigned)o[5] << 16);
    pk.w = o[6] | ((unsigned)o[7] << 16);
    *(uint4*)(out_bf + (size_t)n * OUT_D + dbase) = pk;
  } else if (valid) {
    float r[8];
#pragma unroll
    for (int j = 0; j < 8; ++j) {
      float v = acc[j] + bias[dbase + j];
      r[j] = v >= 0.f ? v : NEG_SLOPE * v;
    }
    *(float4*)(out_f + (size_t)n * OUT_D + dbase) = make_float4(r[0], r[1], r[2], r[3]);
    *(float4*)(out_f + (size_t)n * OUT_D + dbase + 4) = make_float4(r[4], r[5], r[6], r[7]);
  }
}

// ---------------- launch ----------------

extern "C" void kernel_launch(void* const* d_in, const int* in_sizes, int n_in,
                              void* d_out, int out_size, void* d_ws, size_t ws_size,
                              hipStream_t stream) {
  const float* x  = (const float*)d_in[0];   // [50000,256]
  const float* w1 = (const float*)d_in[1];   // [256,256]
  const float* b1 = (const float*)d_in[2];   // [256]
  const float* w2 = (const float*)d_in[3];   // [256,128]
  const float* b2 = (const float*)d_in[4];   // [128]
  const int*   src = (const int*)d_in[5];    // [800000]
  const int*   dst = (const int*)d_in[6];    // [800000]
  const float* ew  = (const float*)d_in[7];  // [800000]
  float* out = (float*)d_out;                // [50000,128]

  unsigned short* xb   = (unsigned short*)d_ws;              // M_PAD*256
  unsigned short* a2b  = xb + (size_t)M_PAD * 256;           // M_PAD*256
  unsigned short* sup1 = a2b + (size_t)M_PAD * 256;          // 8 x [M_PAD][32]
  unsigned short* sup2 = sup1 + (size_t)M_PAD * 256;         // 4 x [M_PAD][32]
  unsigned short* w1T  = sup2 + (size_t)M_PAD * 128;         // 256*256
  unsigned short* w2T  = w1T + 256 * 256;                    // 128*256
  int* counts  = (int*)(w2T + 128 * 256);                    // 50000
  int* cursor  = counts + N_NODES_C;                         // 50000
  int* row_ptr = cursor + N_NODES_C;                         // 50001
  int* partial = row_ptr + (N_NODES_C + 1);                  // 50000
  int* blk_sums= partial + N_NODES_C;                        // 256
  int* blk_off = blk_sums + 256;                             // 256
  uint2* s_meta = (uint2*)(blk_off + 256 + 2);               // 800000 * 8B

  const int EB = (N_EDGES_C + 255) / 256;

  // preprocessing
  hipMemsetAsync(counts, 0, N_NODES_C * sizeof(int), stream);
  pre_kernel<<<NB_PRE, 256, 0, stream>>>(x, w1, w2, dst, xb, w1T, w2T, counts);

  // CSR scan + fill
  scan_phase_a<<<N_SCAN_BLKS, 256, 0, stream>>>(counts, partial, blk_sums);
  scan_phase_b<<<1, 256, 0, stream>>>(blk_sums, blk_off);
  scan_phase_c<<<N_SCAN_BLKS, 256, 0, stream>>>(partial, blk_off, row_ptr, cursor);
  fill_kernel<<<EB, 256, 0, stream>>>(src, dst, ew, cursor, s_meta);

  // layer 1
  gemm_bf16_kernel<<<dim3(2, M_PAD / 128), 256, 0, stream>>>(xb, w1T, sup1, 256);
  {
    const int groups = M_PAD / 64;  // 782
    agg_quad_kernel<8, 256, true><<<groups * 8, 256, 0, stream>>>(
        sup1, s_meta, row_ptr, b1, a2b, nullptr, M_PAD);
  }

  // layer 2
  gemm_bf16_kernel<<<dim3(1, M_PAD / 128), 256, 0, stream>>>(a2b, w2T, sup2, 128);
  {
    const int groups = (N_NODES_C + 63) / 64;  // 782
    agg_quad_kernel<4, 128, false><<<groups * 4, 256, 0, stream>>>(
        sup2, s_meta, row_ptr, b2, nullptr, out, N_NODES_C);
  }
}